// Round 1
// baseline (131.334 us; speedup 1.0000x reference)
//
#include <hip/hip_runtime.h>

#define S_LEN 2048
#define BATCH 8
#define NTOK 64
#define DMODEL 648
#define NBLK (S_LEN / 64)   // 32 blocks of 64 positions

// One workgroup = 512 threads = 8 waves, handles one batch column b.
// grid = (32 chunks, 8 batch). Wave (chunk c, wave wv) processes
// q = c*8 + wv + 256*k for k=0..7  -> each q in [0,2048) exactly once,
// strided so every wave gets a balanced mix of small/large q.
//
// Lane = token id t. Per (q,b):
//   h_i[lane] = #{ j<q : depth(q,j) >= i  and src[j]==lane }   (i=1..4)
//   c_i       = #{ j<q : depth(q,j) >= i }                      (uniform)
//   cu[lane]  = #{ j<q : src[j]==lane }                         (for avg_u)
// depth(q,j) >= i  <=>  src[q-m] == src[j-1-m] for m=0..i-1 (sentinel -1
// for negative positions, both-out-of-range counts as equal).
__global__ __launch_bounds__(512) void embed_kernel(const int* __restrict__ src,
                                                    float* __restrict__ out) {
    __shared__ int src_lds[S_LEN];
    __shared__ unsigned long long Ptab[NBLK * NTOK];  // 16 KB: P[w][t] bitmask

    const int b    = blockIdx.y;
    const int tid  = threadIdx.x;
    const int lane = tid & 63;
    const int wave = tid >> 6;

    // Stage the batch column + build per-block token-position bitmasks.
    for (int i = tid; i < NBLK * NTOK; i += 512) Ptab[i] = 0ull;
    for (int i = tid; i < S_LEN; i += 512) {
        src_lds[i] = src[i * BATCH + b];
    }
    __syncthreads();
    for (int i = tid; i < S_LEN; i += 512) {
        atomicOr(&Ptab[((i >> 6) << 6) | src_lds[i]], 1ull << (i & 63));
    }
    __syncthreads();

    for (int k = 0; k < 8; ++k) {
        const int q = blockIdx.x * 8 + wave + 256 * k;

        const int tq0 = src_lds[q];
        const int tq1 = (q >= 1) ? src_lds[q - 1] : -1;
        const int tq2 = (q >= 2) ? src_lds[q - 2] : -1;
        const int tq3 = (q >= 3) ? src_lds[q - 3] : -1;
        const int tq4 = (q >= 4) ? src_lds[q - 4] : -1;

        int c1 = 0, c2 = 0, c3 = 0, c4 = 0, cu = 0;
        int h1 = 0, h2 = 0, h3 = 0, h4 = 0;

        const int nb = (q + 63) >> 6;  // blocks covering j in [0, q)
        unsigned long long p0 = 0, p1 = 0, p2 = 0, p3 = 0;  // previous-block P

        for (int w = 0; w < nb; ++w) {
            const unsigned long long* Pw = &Ptab[w << 6];
            const unsigned long long q0 = (tq0 >= 0) ? Pw[tq0] : 0ull;
            const unsigned long long q1 = (tq1 >= 0) ? Pw[tq1] : 0ull;
            const unsigned long long q2 = (tq2 >= 0) ? Pw[tq2] : 0ull;
            const unsigned long long q3 = (tq3 >= 0) ? Pw[tq3] : 0ull;

            // comp[m]: bits jj where src[64w+jj-(m+1)] == tq_m (position shift m+1)
            unsigned long long comp0 = (q0 << 1) | (p0 >> 63);
            unsigned long long comp1 = (q1 << 2) | (p1 >> 62);
            unsigned long long comp2 = (q2 << 3) | (p2 >> 61);
            unsigned long long comp3 = (q3 << 4) | (p3 >> 60);
            if (w == 0) {
                // sentinel == sentinel: j-1-m < 0  <=>  jj <= m
                if (tq0 < 0) comp0 |= 0x1ull;
                if (tq1 < 0) comp1 |= 0x3ull;
                if (tq2 < 0) comp2 |= 0x7ull;
                if (tq3 < 0) comp3 |= 0xFull;
            }
            p0 = q0; p1 = q1; p2 = q2; p3 = q3;

            const int rem = q - (w << 6);  // #valid j-bits in this block (j < q)
            const unsigned long long valid =
                (rem >= 64) ? ~0ull : ((1ull << rem) - 1ull);

            const unsigned long long M1 = comp0 & valid;
            const unsigned long long M2 = M1 & comp1;
            const unsigned long long M3 = M2 & comp2;
            const unsigned long long M4 = M3 & comp3;

            c1 += __popcll(M1);
            c2 += __popcll(M2);
            c3 += __popcll(M3);
            c4 += __popcll(M4);

            cu += __popcll(Pw[lane] & valid);  // unconditional prefix histogram

            // Sparse histogram update: ~1 set bit expected per block.
            unsigned long long mrem = M1;
            while (mrem) {
                const int jj = __builtin_ctzll(mrem);
                mrem &= (mrem - 1);
                const unsigned long long bit = 1ull << jj;
                const int sj = src_lds[(w << 6) + jj];
                const int inc = (lane == sj) ? 1 : 0;
                h1 += inc;
                if (M2 & bit) {
                    h2 += inc;
                    if (M3 & bit) {
                        h3 += inc;
                        if (M4 & bit) h4 += inc;
                    }
                }
            }
        }

        float* o = out + ((size_t)q * BATCH + b) * DMODEL;
        // one-hot blocks, offsets 0..4 (sentinel -1 -> all-zero row)
        o[0 * 64 + lane] = (lane == tq0) ? 1.f : 0.f;
        o[1 * 64 + lane] = (lane == tq1) ? 1.f : 0.f;
        o[2 * 64 + lane] = (lane == tq2) ? 1.f : 0.f;
        o[3 * 64 + lane] = (lane == tq3) ? 1.f : 0.f;
        o[4 * 64 + lane] = (lane == tq4) ? 1.f : 0.f;
        // depth-i matched averages
        o[320 + lane] = (float)h1 / (float)(c1 > 0 ? c1 : 1);
        o[384 + lane] = (float)h2 / (float)(c2 > 0 ? c2 : 1);
        o[448 + lane] = (float)h3 / (float)(c3 > 0 ? c3 : 1);
        o[512 + lane] = (float)h4 / (float)(c4 > 0 ? c4 : 1);
        // unconditional causal average
        o[576 + lane] = (float)cu / (float)(q > 0 ? q : 1);
        // counts, q, pad
        if (lane < 8) {
            float v;
            switch (lane) {
                case 0: v = (float)c1; break;
                case 1: v = (float)c2; break;
                case 2: v = (float)c3; break;
                case 3: v = (float)c4; break;
                case 4: v = (float)q;  break;
                default: v = 0.f;      break;
            }
            o[640 + lane] = v;
        }
    }
}

extern "C" void kernel_launch(void* const* d_in, const int* in_sizes, int n_in,
                              void* d_out, int out_size, void* d_ws, size_t ws_size,
                              hipStream_t stream) {
    const int* src = (const int*)d_in[0];
    float* out = (float*)d_out;
    dim3 grid(NBLK, BATCH);  // 32 q-chunks x 8 batch columns
    embed_kernel<<<grid, 512, 0, stream>>>(src, out);
}

// Round 2
// 96.280 us; speedup vs baseline: 1.3641x; 1.3641x over previous
//
#include <hip/hip_runtime.h>

#define S_LEN 2048
#define BATCH 8
#define NTOK 64
#define DMODEL 648
#define NBLK (S_LEN / 64)   // 32 blocks of 64 positions

typedef unsigned long long u64;

// ---------------------------------------------------------------------------
// Kernel 1: per batch column b, build
//   P[b][w][t]  : 64-bit mask of positions 64w+jj (jj bit) with src==t
//   sT[b][i]    : transposed src column
// into workspace. grid = 8 blocks x 512 threads.
// ---------------------------------------------------------------------------
__global__ __launch_bounds__(512) void build_kernel(const int* __restrict__ src,
                                                    u64* __restrict__ P,
                                                    int* __restrict__ sT) {
    __shared__ u64 lp[NBLK * NTOK];
    __shared__ int ls[S_LEN];
    const int b = blockIdx.x;
    const int tid = threadIdx.x;
    for (int i = tid; i < NBLK * NTOK; i += 512) lp[i] = 0ull;
    for (int i = tid; i < S_LEN; i += 512) ls[i] = src[i * BATCH + b];
    __syncthreads();
    for (int i = tid; i < S_LEN; i += 512)
        atomicOr(&lp[((i >> 6) << 6) | ls[i]], 1ull << (i & 63));
    __syncthreads();
    for (int i = tid; i < NBLK * NTOK; i += 512) P[b * (NBLK * NTOK) + i] = lp[i];
    for (int i = tid; i < S_LEN; i += 512) sT[b * S_LEN + i] = ls[i];
}

// ---------------------------------------------------------------------------
// Kernel 2: one wave per (q, b). Lane = token id.
// Wave-uniform mask math runs on SALU via s_load (q passed through
// readfirstlane so the compiler proves uniformity). Per-lane work is one
// coalesced 8B load of P[w][lane] + and/popcount accumulates:
//   h_i[lane] += popcll(M_i & P[w][lane])   (matched next-token histogram)
//   cu[lane]  += popcll(P[w][lane])         (unconditional prefix histogram)
// No LDS, no syncthreads -> full occupancy.
// ---------------------------------------------------------------------------
__global__ __launch_bounds__(256) void compute_kernel(const u64* __restrict__ P,
                                                      const int* __restrict__ sT,
                                                      float* __restrict__ out) {
    const int lane = threadIdx.x & 63;
    int gw = __builtin_amdgcn_readfirstlane(blockIdx.x * 4 + (threadIdx.x >> 6));
    // interleave low/high q per wave index for load balance
    const int q = (gw & 1) ? (S_LEN - 1 - (gw >> 1)) : (gw >> 1);
    const int b = blockIdx.y;

    const int* s = sT + b * S_LEN;
    const u64* Pb = P + (size_t)b * (NBLK * NTOK);

    const int tq0 = s[q];
    const int tq1 = (q >= 1) ? s[q - 1] : -1;
    const int tq2 = (q >= 2) ? s[q - 2] : -1;
    const int tq3 = (q >= 3) ? s[q - 3] : -1;
    const int tq4 = (q >= 4) ? s[q - 4] : -1;

    // row pointers (clamped; clamp only matters when q<4, where wq==0 and the
    // partial block below re-selects 0 explicitly)
    const u64* r0 = Pb + tq0;
    const u64* r1 = Pb + (tq1 >= 0 ? tq1 : 0);
    const u64* r2 = Pb + (tq2 >= 0 ? tq2 : 0);
    const u64* r3 = Pb + (tq3 >= 0 ? tq3 : 0);

    const int wq = q >> 6;
    const int rem = q & 63;

    int c1 = 0, c2 = 0, c3 = 0, c4 = 0;
    int h1 = 0, h2 = 0, h3 = 0, h4 = 0, cu = 0;
    u64 p0 = 0, p1 = 0, p2 = 0, p3 = 0;

    for (int w = 0; w < wq; ++w) {
        const u64 q0 = r0[w << 6];
        const u64 q1 = r1[w << 6];
        const u64 q2 = r2[w << 6];
        const u64 q3 = r3[w << 6];
        // comp[m]: bit jj set iff src[64w+jj-(m+1)] == tq_m
        const u64 comp0 = (q0 << 1) | (p0 >> 63);
        const u64 comp1 = (q1 << 2) | (p1 >> 62);
        const u64 comp2 = (q2 << 3) | (p2 >> 61);
        const u64 comp3 = (q3 << 4) | (p3 >> 60);
        const u64 M1 = comp0;
        const u64 M2 = M1 & comp1;
        const u64 M3 = M2 & comp2;
        const u64 M4 = M3 & comp3;
        c1 += __popcll(M1); c2 += __popcll(M2);
        c3 += __popcll(M3); c4 += __popcll(M4);

        const u64 pv = Pb[(w << 6) + lane];   // per-lane, coalesced
        cu += __popcll(pv);
        h1 += __popcll(M1 & pv);
        if (M2) {
            h2 += __popcll(M2 & pv);
            if (M3) {
                h3 += __popcll(M3 & pv);
                if (M4) h4 += __popcll(M4 & pv);
            }
        }
        p0 = q0; p1 = q1; p2 = q2; p3 = q3;
    }

    if (rem) {  // partial block w = wq, j-bits jj < rem
        const u64 q0 = r0[wq << 6];
        const u64 q1 = (tq1 >= 0) ? r1[wq << 6] : 0ull;
        const u64 q2 = (tq2 >= 0) ? r2[wq << 6] : 0ull;
        const u64 q3 = (tq3 >= 0) ? r3[wq << 6] : 0ull;
        const u64 comp0 = (q0 << 1) | (p0 >> 63);
        const u64 comp1 = (q1 << 2) | (p1 >> 62);
        const u64 comp2 = (q2 << 3) | (p2 >> 61);
        const u64 comp3 = (q3 << 4) | (p3 >> 60);
        const u64 valid = (1ull << rem) - 1ull;
        const u64 M1 = comp0 & valid;
        const u64 M2 = M1 & comp1;
        const u64 M3 = M2 & comp2;
        const u64 M4 = M3 & comp3;
        c1 += __popcll(M1); c2 += __popcll(M2);
        c3 += __popcll(M3); c4 += __popcll(M4);
        const u64 pv = Pb[(wq << 6) + lane];
        cu += __popcll(pv & valid);
        h1 += __popcll(M1 & pv);
        if (M2) {
            h2 += __popcll(M2 & pv);
            if (M3) {
                h3 += __popcll(M3 & pv);
                if (M4) h4 += __popcll(M4 & pv);
            }
        }
    }

    float* o = out + ((size_t)q * BATCH + b) * DMODEL;
    // one-hot blocks, offsets 0..4 (sentinel -1 -> all-zero row)
    o[0 * 64 + lane] = (lane == tq0) ? 1.f : 0.f;
    o[1 * 64 + lane] = (lane == tq1) ? 1.f : 0.f;
    o[2 * 64 + lane] = (lane == tq2) ? 1.f : 0.f;
    o[3 * 64 + lane] = (lane == tq3) ? 1.f : 0.f;
    o[4 * 64 + lane] = (lane == tq4) ? 1.f : 0.f;
    // depth-i matched averages
    o[320 + lane] = (float)h1 / (float)(c1 > 0 ? c1 : 1);
    o[384 + lane] = (float)h2 / (float)(c2 > 0 ? c2 : 1);
    o[448 + lane] = (float)h3 / (float)(c3 > 0 ? c3 : 1);
    o[512 + lane] = (float)h4 / (float)(c4 > 0 ? c4 : 1);
    // unconditional causal average
    o[576 + lane] = (float)cu / (float)(q > 0 ? q : 1);
    // counts, q, pad (zero)
    if (lane < 8) {
        float v;
        switch (lane) {
            case 0: v = (float)c1; break;
            case 1: v = (float)c2; break;
            case 2: v = (float)c3; break;
            case 3: v = (float)c4; break;
            case 4: v = (float)q;  break;
            default: v = 0.f;      break;
        }
        o[640 + lane] = v;
    }
}

extern "C" void kernel_launch(void* const* d_in, const int* in_sizes, int n_in,
                              void* d_out, int out_size, void* d_ws, size_t ws_size,
                              hipStream_t stream) {
    const int* src = (const int*)d_in[0];
    float* out = (float*)d_out;
    u64* P = (u64*)d_ws;                       // 8*2048*8  = 128 KB
    int* sT = (int*)(P + BATCH * NBLK * NTOK); // 8*2048*4  =  64 KB

    build_kernel<<<dim3(BATCH), 512, 0, stream>>>(src, P, sT);
    // 2048 q / 4 waves per 256-thread block = 512 blocks in x, batch in y
    compute_kernel<<<dim3(S_LEN / 4, BATCH), 256, 0, stream>>>(P, sT, out);
}

// Round 3
// 93.792 us; speedup vs baseline: 1.4003x; 1.0265x over previous
//
#include <hip/hip_runtime.h>

typedef unsigned long long u64;

#define S_LEN 2048
#define BATCH 8
#define NTOK 64
#define DMODEL 648
#define NBLK 32   // 32 blocks of 64 positions

// Workspace layout (u64 units):
//   P  [BATCH][NBLK][64] @ 0      : bit jj of P[b][w][t]  = (src[64w+jj]   == t)
//   S1 [BATCH][NBLK][64] @ 16384  : bit jj of S1[b][w][t] = (src[64w+jj-1] == t)
//   S2 [BATCH][NBLK][64] @ 32768  : bit jj of S2[b][w][t] = (src[64w+jj-2] == t)
//   sT [BATCH][S_LEN]    @ 49152  : transposed src column (int)

// ---------------------------------------------------------------------------
// Build: one 64-thread wave per (block w, batch b). Lane j holds token at
// position 64w+j; per-token masks via __ballot. Pre-shifted tables S1/S2
// computed with the previous block's ballot for the cross-block carry.
// ---------------------------------------------------------------------------
__global__ __launch_bounds__(64) void build_kernel(const int* __restrict__ src,
                                                   u64* __restrict__ P,
                                                   u64* __restrict__ S1,
                                                   u64* __restrict__ S2,
                                                   int* __restrict__ sT) {
    const int w = blockIdx.x, b = blockIdx.y;
    const int lane = threadIdx.x;
    const int p = (w << 6) + lane;
    const int tok  = src[p * BATCH + b];
    const int tokp = (w > 0) ? src[(p - 64) * BATCH + b] : -1;  // prev block
    u64 m_sel = 0, mp_sel = 0;
    #pragma unroll 8
    for (int t = 0; t < NTOK; ++t) {
        const u64 m  = __ballot(tok == t);
        const u64 mp = __ballot(tokp == t);
        if (lane == t) { m_sel = m; mp_sel = mp; }
    }
    const int base = ((b * NBLK) + w) * 64 + lane;
    P[base]  = m_sel;
    S1[base] = (m_sel << 1) | (mp_sel >> 63);
    S2[base] = (m_sel << 2) | (mp_sel >> 62);
    sT[b * S_LEN + p] = tok;
}

// ---------------------------------------------------------------------------
// Compute: WG = 256 threads = 4 waves; each wave owns 8 consecutive q
// (one "octet") of one batch column. Lane = token id.
//   M1(q) = Sh1[w][s[q]]                (depth>=1 match bits, j in block w)
//   M2(q) = M1 & Sh2[w][s[q-1]]         (depth>=2)
//   M3(q) = M2 & shift1(Sh2[w][s[q-2]]) (depth>=3, rare path)
//   M4(q) = M3 & shift2(Sh2[w][s[q-3]]) (depth>=4, rare path)
//   h_i[lane] += popc(M_i & P[w][lane]) ; c_i = sum over lanes of h_i.
// Octets paired low/high across the grid for load balance.
// ---------------------------------------------------------------------------
__global__ __launch_bounds__(256, 4) void compute_kernel(const u64* __restrict__ P,
                                                         const u64* __restrict__ S1g,
                                                         const u64* __restrict__ S2g,
                                                         const int* __restrict__ sT,
                                                         float* __restrict__ out) {
    __shared__ u64 L1s[S_LEN];  // Sh1[b]
    __shared__ u64 L2s[S_LEN];  // Sh2[b]

    const int b = blockIdx.y;
    const int tid = threadIdx.x;
    const int lane = tid & 63;
    const int wv = tid >> 6;

    for (int i = tid; i < S_LEN; i += 256) {
        L1s[i] = S1g[b * S_LEN + i];
        L2s[i] = S2g[b * S_LEN + i];
    }
    __syncthreads();

    const int o = blockIdx.x * 4 + wv;                    // 0..255
    const int qoct = (o & 1) ? (255 - (o >> 1)) : (o >> 1);
    const int q0 = qoct << 3;

    const int* s = sT + b * S_LEN;
    const u64* Pb = P + (size_t)b * (NBLK * 64);

    int tk[12];
    #pragma unroll
    for (int i = 0; i < 12; ++i) {
        const int idx = q0 - 4 + i;
        tk[i] = (idx >= 0) ? s[idx] : 0;   // clamp; provably safe (see notes)
    }

    int hh[8][4] = {};
    int cuP[8];
    int cuF = 0;
    const int wq = q0 >> 6, rem0 = q0 & 63;

    u64 pv = Pb[lane];  // block 0 per-lane token mask
    for (int w = 0; w < wq; ++w) {
        const u64 pvn = Pb[((w + 1) << 6) + lane];  // prefetch next block
        cuF += __popcll(pv);
        const int wb = w << 6;
        #pragma unroll
        for (int r = 0; r < 8; ++r) {
            const u64 M1 = L1s[wb + tk[4 + r]];
            const u64 M2 = M1 & L2s[wb + tk[3 + r]];
            hh[r][0] += __popcll(M1 & pv);
            if (__builtin_amdgcn_readfirstlane((unsigned)M2 | (unsigned)(M2 >> 32))) {
                const u64 c2c = L2s[wb + tk[2 + r]];
                const u64 c2p = (w > 0) ? L2s[wb - 64 + tk[2 + r]] : 0;
                const u64 c3c = L2s[wb + tk[1 + r]];
                const u64 c3p = (w > 0) ? L2s[wb - 64 + tk[1 + r]] : 0;
                const u64 M3 = M2 & ((c2c << 1) | (c2p >> 63));
                const u64 M4 = M3 & ((c3c << 2) | (c3p >> 62));
                hh[r][1] += __popcll(M2 & pv);
                hh[r][2] += __popcll(M3 & pv);
                hh[r][3] += __popcll(M4 & pv);
            }
        }
        pv = pvn;
    }

    {   // partial block w = wq (j-bits jj < rem0 + r); pv already holds it
        const int wb = wq << 6;
        #pragma unroll
        for (int r = 0; r < 8; ++r) {
            const int rem = rem0 + r;                  // <= 63 always
            const u64 valid = (1ull << rem) - 1ull;    // rem==0 -> 0
            cuP[r] = cuF + __popcll(pv & valid);
            const u64 M1 = L1s[wb + tk[4 + r]] & valid;
            const u64 M2 = M1 & L2s[wb + tk[3 + r]];
            hh[r][0] += __popcll(M1 & pv);
            if (__builtin_amdgcn_readfirstlane((unsigned)M2 | (unsigned)(M2 >> 32))) {
                const u64 c2c = L2s[wb + tk[2 + r]];
                const u64 c2p = (wq > 0) ? L2s[wb - 64 + tk[2 + r]] : 0;
                const u64 c3c = L2s[wb + tk[1 + r]];
                const u64 c3p = (wq > 0) ? L2s[wb - 64 + tk[1 + r]] : 0;
                const u64 M3 = M2 & ((c2c << 1) | (c2p >> 63));
                const u64 M4 = M3 & ((c3c << 2) | (c3p >> 62));
                hh[r][1] += __popcll(M2 & pv);
                hh[r][2] += __popcll(M3 & pv);
                hh[r][3] += __popcll(M4 & pv);
            }
        }
    }

    // Epilogue: c_i = wave-sum of h_i (packed 2x16-bit), then write 648 chans.
    #pragma unroll
    for (int r = 0; r < 8; ++r) {
        const int q = q0 + r;
        int p01 = hh[r][0] | (hh[r][1] << 16);
        int p23 = hh[r][2] | (hh[r][3] << 16);
        #pragma unroll
        for (int sft = 1; sft < 64; sft <<= 1) {
            p01 += __shfl_xor(p01, sft);
            p23 += __shfl_xor(p23, sft);
        }
        const int c1 = p01 & 0xffff, c2 = p01 >> 16;
        const int c3 = p23 & 0xffff, c4 = p23 >> 16;

        float* op = out + ((size_t)q * BATCH + b) * DMODEL;
        #pragma unroll
        for (int m = 0; m <= 4; ++m) {   // one-hot blocks, sentinel -> zeros
            const bool sent = (q0 + r - m) < 0;
            op[m * 64 + lane] = (!sent && lane == tk[4 + r - m]) ? 1.f : 0.f;
        }
        op[320 + lane] = (float)hh[r][0] / (float)(c1 ? c1 : 1);
        op[384 + lane] = (float)hh[r][1] / (float)(c2 ? c2 : 1);
        op[448 + lane] = (float)hh[r][2] / (float)(c3 ? c3 : 1);
        op[512 + lane] = (float)hh[r][3] / (float)(c4 ? c4 : 1);
        op[576 + lane] = (float)cuP[r] / (float)(q ? q : 1);
        if (lane < 8) {
            float v = 0.f;
            if (lane == 0) v = (float)c1;
            else if (lane == 1) v = (float)c2;
            else if (lane == 2) v = (float)c3;
            else if (lane == 3) v = (float)c4;
            else if (lane == 4) v = (float)q;
            op[640 + lane] = v;
        }
    }
}

extern "C" void kernel_launch(void* const* d_in, const int* in_sizes, int n_in,
                              void* d_out, int out_size, void* d_ws, size_t ws_size,
                              hipStream_t stream) {
    const int* src = (const int*)d_in[0];
    float* out = (float*)d_out;
    u64* P  = (u64*)d_ws;
    u64* S1 = P + 16384;
    u64* S2 = P + 32768;
    int* sT = (int*)(P + 49152);

    build_kernel<<<dim3(NBLK, BATCH), 64, 0, stream>>>(src, P, S1, S2, sT);
    // 256 octets per b / 4 waves per WG -> grid (64, 8)
    compute_kernel<<<dim3(64, BATCH), 256, 0, stream>>>(P, S1, S2, sT, out);
}